// Round 1
// baseline (3658.842 us; speedup 1.0000x reference)
//
#include <hip/hip_runtime.h>

// Problem constants (from reference setup_inputs)
#define SZ0 1363968
#define SZ1 123904
#define SZ2 11264
#define SZ3 1024
#define NE0 1239040
#define NE1 112640
#define NE2 10240
#define DIN 128
#define DH  256
#define DOUT 64

// ---------------------------------------------------------------------------
// Edge scatter: agg[dst] += X[src], cnt[dst] += 1   (mean computed later)
// One thread handles 4 features of one edge (float4 read, 4 scalar atomics).
// D is a power of two and E*D/4 is an exact multiple of 256 -> no guards.
// ---------------------------------------------------------------------------
template <int D>
__global__ __launch_bounds__(256) void scatter_accum(
    const float* __restrict__ X, const int* __restrict__ src,
    const int* __restrict__ dst, float* __restrict__ agg,
    float* __restrict__ cnt)
{
    constexpr int PER = D / 4;                 // threads per edge
    int gid = blockIdx.x * 256 + threadIdx.x;  // < E*PER < 2^31
    int e = gid / PER;
    int r = gid % PER;
    int s = src[e];
    int d = dst[e];
    const float4 v = *reinterpret_cast<const float4*>(X + (size_t)s * D + r * 4);
    float* o = agg + (size_t)d * D + r * 4;
    atomicAdd(o + 0, v.x);
    atomicAdd(o + 1, v.y);
    atomicAdd(o + 2, v.z);
    atomicAdd(o + 3, v.w);
    if (r == 0) atomicAdd(cnt + d, 1.0f);
}

// ---------------------------------------------------------------------------
// Fused SAGE GEMM:
//   C[m][n] = act( (agg[m]/max(cnt[m],1)) . B1[:,n]  +  A2[m] . B2[:,n] + bias[n] )
// i.e. a (M x (K1+K2)) @ ((K1+K2) x N) GEMM where the A matrix is the
// concatenation [mean | A2] built on the fly.
// Tiling: BM=BN=64, BK=32, 256 threads, 4x4 register tile per thread.
// Requires: M%64==0, N%64==0, K1%32==0, K2%32==0 (true for all 3 layers).
// ---------------------------------------------------------------------------
__global__ __launch_bounds__(256) void gemm_sage(
    const float* __restrict__ A1, const float* __restrict__ cnt,
    const float* __restrict__ A2,
    const float* __restrict__ B1, const float* __restrict__ B2,
    const float* __restrict__ bias, float* __restrict__ C,
    int M, int N, int K1, int K2, int do_relu)
{
    __shared__ float As[64][33];   // [m][k]  (+1 pad)
    __shared__ float Bs[32][68];   // [k][n]  (+4 pad keeps float4 alignment)
    __shared__ float invC[64];

    const int tid = threadIdx.x;
    const int m0 = blockIdx.y * 64;
    const int n0 = blockIdx.x * 64;

    if (tid < 64) {
        invC[tid] = 1.0f / fmaxf(cnt[m0 + tid], 1.0f);
    }
    __syncthreads();

    const int K = K1 + K2;
    const int arow = tid >> 5;   // 0..7   (A tile: 64 rows x 32 cols)
    const int acol = tid & 31;
    const int brow = tid >> 6;   // 0..3   (B tile: 32 rows x 64 cols)
    const int bcol = tid & 63;
    const int ty = tid >> 4;     // 0..15
    const int tx = tid & 15;     // 0..15

    float acc[4][4];
#pragma unroll
    for (int i = 0; i < 4; i++)
#pragma unroll
        for (int j = 0; j < 4; j++) acc[i][j] = 0.0f;

    for (int kt = 0; kt < K; kt += 32) {
        // ---- stage A tile (scaled by 1/cnt for the agg half) ----
        if (kt + 31 < K1) {
#pragma unroll
            for (int i = 0; i < 8; i++) {
                int row = arow + i * 8;
                As[row][acol] = A1[(size_t)(m0 + row) * K1 + kt + acol] * invC[row];
            }
        } else {
#pragma unroll
            for (int i = 0; i < 8; i++) {
                int row = arow + i * 8;
                As[row][acol] = A2[(size_t)(m0 + row) * K2 + (kt - K1) + acol];
            }
        }
        // ---- stage B tile ----
        if (kt + 31 < K1) {
#pragma unroll
            for (int i = 0; i < 8; i++) {
                int row = brow + i * 4;
                Bs[row][bcol] = B1[(size_t)(kt + row) * N + n0 + bcol];
            }
        } else {
#pragma unroll
            for (int i = 0; i < 8; i++) {
                int row = brow + i * 4;
                Bs[row][bcol] = B2[(size_t)(kt - K1 + row) * N + n0 + bcol];
            }
        }
        __syncthreads();

        // ---- 64x64 tile FMA ----
#pragma unroll
        for (int kk = 0; kk < 32; kk++) {
            float a[4];
#pragma unroll
            for (int i = 0; i < 4; i++) a[i] = As[ty * 4 + i][kk];
            const float4 b4 = *reinterpret_cast<const float4*>(&Bs[kk][tx * 4]);
            const float b[4] = {b4.x, b4.y, b4.z, b4.w};
#pragma unroll
            for (int i = 0; i < 4; i++)
#pragma unroll
                for (int j = 0; j < 4; j++) acc[i][j] += a[i] * b[j];
        }
        __syncthreads();
    }

    // ---- epilogue: + bias, optional relu, float4 store ----
    const float4 bb = *reinterpret_cast<const float4*>(bias + n0 + tx * 4);
    const float bv[4] = {bb.x, bb.y, bb.z, bb.w};
#pragma unroll
    for (int i = 0; i < 4; i++) {
        int row = m0 + ty * 4 + i;
        float4 o;
        float v0 = acc[i][0] + bv[0];
        float v1 = acc[i][1] + bv[1];
        float v2 = acc[i][2] + bv[2];
        float v3 = acc[i][3] + bv[3];
        if (do_relu) {
            v0 = fmaxf(v0, 0.0f); v1 = fmaxf(v1, 0.0f);
            v2 = fmaxf(v2, 0.0f); v3 = fmaxf(v3, 0.0f);
        }
        o.x = v0; o.y = v1; o.z = v2; o.w = v3;
        *reinterpret_cast<float4*>(C + (size_t)row * N + n0 + tx * 4) = o;
    }
}

extern "C" void kernel_launch(void* const* d_in, const int* in_sizes, int n_in,
                              void* d_out, int out_size, void* d_ws, size_t ws_size,
                              hipStream_t stream)
{
    const float* x   = (const float*)d_in[0];
    const float* Wl0 = (const float*)d_in[1];
    const float* bl0 = (const float*)d_in[2];
    const float* Wr0 = (const float*)d_in[3];
    const float* Wl1 = (const float*)d_in[4];
    const float* bl1 = (const float*)d_in[5];
    const float* Wr1 = (const float*)d_in[6];
    const float* Wl2 = (const float*)d_in[7];
    const float* bl2 = (const float*)d_in[8];
    const float* Wr2 = (const float*)d_in[9];
    const int* es0 = (const int*)d_in[10];
    const int* ed0 = (const int*)d_in[11];
    const int* es1 = (const int*)d_in[12];
    const int* ed1 = (const int*)d_in[13];
    const int* es2 = (const int*)d_in[14];
    const int* ed2 = (const int*)d_in[15];

    // Workspace layout (floats). Zeroed region first (agg/cnt), then h1/h2.
    float* ws = (float*)d_ws;
    float* agg0 = ws;                               // SZ1*DIN = 15,859,712
    float* cnt0 = agg0 + (size_t)SZ1 * DIN;         // SZ1
    float* agg1 = cnt0 + SZ1;                       // SZ2*DH = 2,883,584
    float* cnt1 = agg1 + (size_t)SZ2 * DH;          // SZ2
    float* agg2 = cnt1 + SZ2;                       // SZ3*DH = 262,144
    float* cnt2 = agg2 + (size_t)SZ3 * DH;          // SZ3
    float* zend = cnt2 + SZ3;
    float* h1   = zend;                             // SZ1*DH = 31,719,424
    float* h2   = h1 + (size_t)SZ1 * DH;            // SZ2*DH
    // total: ~205 MiB

    // d_ws is re-poisoned to 0xAA before every launch -> zero agg/cnt each call
    size_t zbytes = (size_t)(zend - ws) * sizeof(float);
    hipMemsetAsync(d_ws, 0, zbytes, stream);

    // ---- layer 0: x(1363968x128) -> h1(123904x256), relu ----
    scatter_accum<DIN><<<NE0 * (DIN / 4) / 256, 256, 0, stream>>>(x, es0, ed0, agg0, cnt0);
    gemm_sage<<<dim3(DH / 64, SZ1 / 64), 256, 0, stream>>>(
        agg0, cnt0, x, Wl0, Wr0, bl0, h1, SZ1, DH, DIN, DIN, 1);

    // ---- layer 1: h1 -> h2(11264x256), no relu ----
    scatter_accum<DH><<<NE1 * (DH / 4) / 256, 256, 0, stream>>>(h1, es1, ed1, agg1, cnt1);
    gemm_sage<<<dim3(DH / 64, SZ2 / 64), 256, 0, stream>>>(
        agg1, cnt1, h1, Wl1, Wr1, bl1, h2, SZ2, DH, DH, DH, 0);

    // ---- layer 2: h2 -> out(1024x64), relu ----
    scatter_accum<DH><<<NE2 * (DH / 4) / 256, 256, 0, stream>>>(h2, es2, ed2, agg2, cnt2);
    gemm_sage<<<dim3(DOUT / 64, SZ3 / 64), 256, 0, stream>>>(
        agg2, cnt2, h2, Wl2, Wr2, bl2, (float*)d_out, SZ3, DOUT, DH, DH, 1);
}

// Round 2
// 1901.815 us; speedup vs baseline: 1.9239x; 1.9239x over previous
//
#include <hip/hip_runtime.h>

// Problem constants (from reference setup_inputs)
#define SZ0 1363968
#define SZ1 123904
#define SZ2 11264
#define SZ3 1024
#define NE0 1239040
#define NE1 112640
#define NE2 10240
#define DIN 128
#define DH  256
#define DOUT 64

// ---------------------------------------------------------------------------
// 1) Degree histogram: bk[dst]++  (int atomics, E total, ~10 per counter)
// ---------------------------------------------------------------------------
__global__ __launch_bounds__(256) void edge_hist(
    const int* __restrict__ dst, int* __restrict__ bk, int E)
{
    int e = blockIdx.x * 256 + threadIdx.x;
    if (e < E) atomicAdd(&bk[dst[e]], 1);
}

// ---------------------------------------------------------------------------
// 2) In-place exclusive scan over n counters (single 1024-thread block).
//    n is a multiple of 1024 for all layers -> every chunk is full.
// ---------------------------------------------------------------------------
__global__ __launch_bounds__(1024) void scan_inplace(int* __restrict__ a, int n)
{
    __shared__ int sums[1024];
    const int t = threadIdx.x;
    const int C = (n + 1023) >> 10;
    const int lo = t * C;
    const int hi = min(lo + C, n);
    int s = 0;
    for (int i = lo; i < hi; i++) s += a[i];
    sums[t] = s;
    __syncthreads();
    for (int off = 1; off < 1024; off <<= 1) {
        int v = (t >= off) ? sums[t - off] : 0;
        __syncthreads();
        sums[t] += v;
        __syncthreads();
    }
    int pre = (t == 0) ? 0 : sums[t - 1];
    for (int i = lo; i < hi; i++) { int v = a[i]; a[i] = pre; pre += v; }
}

// ---------------------------------------------------------------------------
// 3) Ticket-scatter src into dst-sorted buckets. After this kernel,
//    bk[d] == end offset of bucket d (start = bk[d-1], or 0 for d==0).
// ---------------------------------------------------------------------------
__global__ __launch_bounds__(256) void edge_bucket(
    const int* __restrict__ src, const int* __restrict__ dst,
    int* __restrict__ bk, int* __restrict__ perm, int E)
{
    int e = blockIdx.x * 256 + threadIdx.x;
    if (e < E) {
        int pos = atomicAdd(&bk[dst[e]], 1);
        perm[pos] = src[e];
    }
}

// ---------------------------------------------------------------------------
// 4) Segmented gather-mean: one wave (64 lanes) per dst row.
//    D=128 -> float2/lane, D=256 -> float4/lane. 512B/1KB contiguous per row.
//    Writes EVERY row (0 for empty buckets) -> no pre-zeroing of out needed.
// ---------------------------------------------------------------------------
template <int D>
__global__ __launch_bounds__(256) void gather_mean(
    const float* __restrict__ X, const int* __restrict__ perm,
    const int* __restrict__ ends, float* __restrict__ out)
{
    constexpr int VEC = D / 64;
    const int wave = (blockIdx.x * 256 + threadIdx.x) >> 6;
    const int lane = threadIdx.x & 63;
    const int start = (wave == 0) ? 0 : ends[wave - 1];
    const int end = ends[wave];

    float acc[VEC];
#pragma unroll
    for (int i = 0; i < VEC; i++) acc[i] = 0.0f;

    for (int e = start; e < end; e++) {
        int s = perm[e];
        const float* p = X + (size_t)s * D + lane * VEC;
        if (VEC == 2) {
            float2 v = *reinterpret_cast<const float2*>(p);
            acc[0] += v.x; acc[1] += v.y;
        } else {
            float4 v = *reinterpret_cast<const float4*>(p);
            acc[0] += v.x; acc[1] += v.y; acc[2] += v.z; acc[3] += v.w;
        }
    }

    const float inv = 1.0f / (float)max(end - start, 1);
    float* o = out + (size_t)wave * D + lane * VEC;
    if (VEC == 2) {
        float2 v; v.x = acc[0] * inv; v.y = acc[1] * inv;
        *reinterpret_cast<float2*>(o) = v;
    } else {
        float4 v; v.x = acc[0] * inv; v.y = acc[1] * inv;
        v.z = acc[2] * inv; v.w = acc[3] * inv;
        *reinterpret_cast<float4*>(o) = v;
    }
}

// ---------------------------------------------------------------------------
// Fused SAGE GEMM: C[m][n] = act( mean[m].B1[:,n] + A2[m].B2[:,n] + bias[n] )
// A = [mean | A2] concatenated on the fly; BM=BN=64, BK=32, 256 thr, 4x4/thr.
// ---------------------------------------------------------------------------
__global__ __launch_bounds__(256) void gemm_sage(
    const float* __restrict__ A1, const float* __restrict__ A2,
    const float* __restrict__ B1, const float* __restrict__ B2,
    const float* __restrict__ bias, float* __restrict__ C,
    int M, int N, int K1, int K2, int do_relu)
{
    __shared__ float As[64][33];   // [m][k]  (+1 pad)
    __shared__ float Bs[32][68];   // [k][n]  (+4 pad keeps float4 alignment)

    const int tid = threadIdx.x;
    const int m0 = blockIdx.y * 64;
    const int n0 = blockIdx.x * 64;

    const int K = K1 + K2;
    const int arow = tid >> 5;   // 0..7   (A tile: 64 rows x 32 cols)
    const int acol = tid & 31;
    const int brow = tid >> 6;   // 0..3   (B tile: 32 rows x 64 cols)
    const int bcol = tid & 63;
    const int ty = tid >> 4;     // 0..15
    const int tx = tid & 15;     // 0..15

    float acc[4][4];
#pragma unroll
    for (int i = 0; i < 4; i++)
#pragma unroll
        for (int j = 0; j < 4; j++) acc[i][j] = 0.0f;

    for (int kt = 0; kt < K; kt += 32) {
        if (kt < K1) {
#pragma unroll
            for (int i = 0; i < 8; i++) {
                int row = arow + i * 8;
                As[row][acol] = A1[(size_t)(m0 + row) * K1 + kt + acol];
            }
        } else {
#pragma unroll
            for (int i = 0; i < 8; i++) {
                int row = arow + i * 8;
                As[row][acol] = A2[(size_t)(m0 + row) * K2 + (kt - K1) + acol];
            }
        }
        if (kt < K1) {
#pragma unroll
            for (int i = 0; i < 8; i++) {
                int row = brow + i * 4;
                Bs[row][bcol] = B1[(size_t)(kt + row) * N + n0 + bcol];
            }
        } else {
#pragma unroll
            for (int i = 0; i < 8; i++) {
                int row = brow + i * 4;
                Bs[row][bcol] = B2[(size_t)(kt - K1 + row) * N + n0 + bcol];
            }
        }
        __syncthreads();

#pragma unroll
        for (int kk = 0; kk < 32; kk++) {
            float a[4];
#pragma unroll
            for (int i = 0; i < 4; i++) a[i] = As[ty * 4 + i][kk];
            const float4 b4 = *reinterpret_cast<const float4*>(&Bs[kk][tx * 4]);
            const float b[4] = {b4.x, b4.y, b4.z, b4.w};
#pragma unroll
            for (int i = 0; i < 4; i++)
#pragma unroll
                for (int j = 0; j < 4; j++) acc[i][j] += a[i] * b[j];
        }
        __syncthreads();
    }

    const float4 bb = *reinterpret_cast<const float4*>(bias + n0 + tx * 4);
    const float bv[4] = {bb.x, bb.y, bb.z, bb.w};
#pragma unroll
    for (int i = 0; i < 4; i++) {
        int row = m0 + ty * 4 + i;
        float v0 = acc[i][0] + bv[0];
        float v1 = acc[i][1] + bv[1];
        float v2 = acc[i][2] + bv[2];
        float v3 = acc[i][3] + bv[3];
        if (do_relu) {
            v0 = fmaxf(v0, 0.0f); v1 = fmaxf(v1, 0.0f);
            v2 = fmaxf(v2, 0.0f); v3 = fmaxf(v3, 0.0f);
        }
        float4 o; o.x = v0; o.y = v1; o.z = v2; o.w = v3;
        *reinterpret_cast<float4*>(C + (size_t)row * N + n0 + tx * 4) = o;
    }
}

extern "C" void kernel_launch(void* const* d_in, const int* in_sizes, int n_in,
                              void* d_out, int out_size, void* d_ws, size_t ws_size,
                              hipStream_t stream)
{
    const float* x   = (const float*)d_in[0];
    const float* Wl0 = (const float*)d_in[1];
    const float* bl0 = (const float*)d_in[2];
    const float* Wr0 = (const float*)d_in[3];
    const float* Wl1 = (const float*)d_in[4];
    const float* bl1 = (const float*)d_in[5];
    const float* Wr1 = (const float*)d_in[6];
    const float* Wl2 = (const float*)d_in[7];
    const float* bl2 = (const float*)d_in[8];
    const float* Wr2 = (const float*)d_in[9];
    const int* es0 = (const int*)d_in[10];
    const int* ed0 = (const int*)d_in[11];
    const int* es1 = (const int*)d_in[12];
    const int* ed1 = (const int*)d_in[13];
    const int* es2 = (const int*)d_in[14];
    const int* ed2 = (const int*)d_in[15];

    // Workspace layout (4B units). Only bk* needs zeroing.
    int* bk0   = (int*)d_ws;                       // SZ1
    int* bk1   = bk0 + SZ1;                        // SZ2
    int* bk2   = bk1 + SZ2;                        // SZ3
    int* perm0 = bk2 + SZ3;                        // NE0
    int* perm1 = perm0 + NE0;                      // NE1
    int* perm2 = perm1 + NE1;                      // NE2
    float* agg0 = (float*)(perm2 + NE2);           // SZ1*DIN
    float* agg1 = agg0 + (size_t)SZ1 * DIN;        // SZ2*DH
    float* agg2 = agg1 + (size_t)SZ2 * DH;         // SZ3*DH
    float* h1   = agg2 + (size_t)SZ3 * DH;         // SZ1*DH
    float* h2   = agg0;  // alias: agg0 is dead after gemm0; SZ2*DH <= SZ1*DIN
    // total distinct: ~208.9 MB

    hipMemsetAsync(bk0, 0, (size_t)(SZ1 + SZ2 + SZ3) * sizeof(int), stream);

    // ---- layer 0: x(1363968x128) -> h1(123904x256), relu ----
    edge_hist<<<(NE0 + 255) / 256, 256, 0, stream>>>(ed0, bk0, NE0);
    scan_inplace<<<1, 1024, 0, stream>>>(bk0, SZ1);
    edge_bucket<<<(NE0 + 255) / 256, 256, 0, stream>>>(es0, ed0, bk0, perm0, NE0);
    gather_mean<DIN><<<SZ1 / 4, 256, 0, stream>>>(x, perm0, bk0, agg0);
    gemm_sage<<<dim3(DH / 64, SZ1 / 64), 256, 0, stream>>>(
        agg0, x, Wl0, Wr0, bl0, h1, SZ1, DH, DIN, DIN, 1);

    // ---- layer 1: h1 -> h2(11264x256), no relu ----
    edge_hist<<<(NE1 + 255) / 256, 256, 0, stream>>>(ed1, bk1, NE1);
    scan_inplace<<<1, 1024, 0, stream>>>(bk1, SZ2);
    edge_bucket<<<(NE1 + 255) / 256, 256, 0, stream>>>(es1, ed1, bk1, perm1, NE1);
    gather_mean<DH><<<SZ2 / 4, 256, 0, stream>>>(h1, perm1, bk1, agg1);
    gemm_sage<<<dim3(DH / 64, SZ2 / 64), 256, 0, stream>>>(
        agg1, h1, Wl1, Wr1, bl1, h2, SZ2, DH, DH, DH, 0);

    // ---- layer 2: h2 -> out(1024x64), relu ----
    edge_hist<<<(NE2 + 255) / 256, 256, 0, stream>>>(ed2, bk2, NE2);
    scan_inplace<<<1, 1024, 0, stream>>>(bk2, SZ3);
    edge_bucket<<<(NE2 + 255) / 256, 256, 0, stream>>>(es2, ed2, bk2, perm2, NE2);
    gather_mean<DH><<<SZ3 / 4, 256, 0, stream>>>(h2, perm2, bk2, agg2);
    gemm_sage<<<dim3(DOUT / 64, SZ3 / 64), 256, 0, stream>>>(
        agg2, h2, Wl2, Wr2, bl2, (float*)d_out, SZ3, DOUT, DH, DH, 1);
}